// Round 9
// baseline (387.941 us; speedup 1.0000x reference)
//
#include <hip/hip_runtime.h>
#include <hip/hip_bf16.h>

// Problem constants (fixed by reference): N=262144 rows, D=64, K=512 codes.
#define N_ROWS 262144
#define DIM 64
#define KC 512
#define BLK 512                        // threads/block; 8 waves = 2/SIMD, 1 block/CU
#define RPT 2                          // rows per thread
#define LDS_FLOATS (KC * DIM + KC)     // codebook + esq = 33280 floats = 133120 B

// d_out layout — FLOAT32 (verified passing):
//   out[0]                      = loss
//   out[1 .. 1+N*D)             = quantized [N,64] row-major
//   out[1+N*D .. 1+N*D+N)       = float(encoding_indices)
//
// Numerics replicated exactly (indices must match np.argmin of f32 dists):
//   x_sq, e_sq : numpy pairwise sum, n=64 => 8-accumulator striped scheme
//   dot        : sequential fused-FMA chain, ascending j (OpenBLAS kernel)
//   d          : fl( fl(x_sq + e_sq_k) - 2*dot_k ), contraction off
//   argmin     : strict <, first-min-wins (k ascending)
//
// R8 post-mortem: 330->276us. VALU busy-time 177us (= 109us scalar-FMA
// floor + overhead) is now the wall; LDS delivery ~109us; ~100us stall gap.
// Occupancy structurally capped at 2 waves/SIMD (full-codebook LDS => 1
// block/CU; RPT=4 needs 256 VGPRs for x alone => dead).
// R9: v_pk_fma_f32 — the ONLY path to the 157 TF fp32 peak (2x scalar
// v_fmac rate). Two INDEPENDENT IEEE f32 FMAs per instr: row0 chain in lo
// half, row1 chain in hi half => each chain stays the bit-exact sequential
// fused-FMA in ascending j. e broadcast to both halves via op_sel_hi
// (VOP3P modifier), zero duplication movs. Each pk-FMA is a single-instr
// asm with tied "+v" accumulator: no cross-asm register state (the R4/R6
// unsoundness class doesn't apply). FMA issue demand halves: 109 -> 55us.

// v_pk_fma_f32 acc, xp, e2, acc — broadcast LOW half of e2 to both lanes:
//   lo: acc.x = fma(xp.x, e2.x, acc.x)   hi: acc.y = fma(xp.y, e2.x, acc.y)
#define PK_FMA_ELO(acc, xp_, e2_) \
    asm("v_pk_fma_f32 %0, %1, %2, %0 op_sel_hi:[1,0,1]" \
        : "+v"(acc) : "v"(xp_), "v"(e2_))
// broadcast HIGH half of e2 to both lanes:
//   lo: acc.x = fma(xp.x, e2.y, acc.x)   hi: acc.y = fma(xp.y, e2.y, acc.y)
#define PK_FMA_EHI(acc, xp_, e2_) \
    asm("v_pk_fma_f32 %0, %1, %2, %0 op_sel:[0,1,0] op_sel_hi:[1,1,1]" \
        : "+v"(acc) : "v"(xp_), "v"(e2_))

// numpy pairwise sum of squares for n=64 (scalar path, PW_BLOCKSIZE=128).
__device__ __forceinline__ float np_sumsq64(const float* a) {
#pragma clang fp contract(off)
    float r[8];
#pragma unroll
    for (int j = 0; j < 8; ++j) r[j] = a[j] * a[j];
#pragma unroll
    for (int i = 8; i < 64; i += 8)
#pragma unroll
        for (int j = 0; j < 8; ++j) r[j] = r[j] + a[i + j] * a[i + j];
    return ((r[0] + r[1]) + (r[2] + r[3])) + ((r[4] + r[5]) + (r[6] + r[7]));
}

// ---- kernel 1: e_sq_k with numpy bit-exact summation ----
__global__ void esq_kernel(const float* __restrict__ cb, float* __restrict__ esq) {
    int k = blockIdx.x * blockDim.x + threadIdx.x;
    if (k < KC) esq[k] = np_sumsq64(cb + k * DIM);
}

// ---- kernel 2: main VQ — TWO rows per thread (packed), codebook in LDS ----
__global__ __launch_bounds__(BLK)
__attribute__((amdgpu_waves_per_eu(2, 2)))   // grid-exact occupancy; 256-VGPR budget
void vq_kernel(
    const float* __restrict__ x, const float* __restrict__ cb,
    const float* __restrict__ esq_g, float* __restrict__ out,
    float* __restrict__ loss_acc)
{
    extern __shared__ float smem[];
    float* cbs  = smem;             // [512*64] codebook, k-major (global layout)
    float* esql = smem + KC * DIM;  // [512]

    const int tid  = threadIdx.x;
    const int lane = tid & 63;
    const int row0 = blockIdx.x * (BLK * RPT) + tid;   // rows row0 and row0+BLK
    const int row1 = row0 + BLK;

    // ---- cooperative stage: 128KB codebook + 2KB esq, fully coalesced ----
    {
        const float4* g4 = reinterpret_cast<const float4*>(cb);
        float4*       s4 = reinterpret_cast<float4*>(cbs);
#pragma unroll
        for (int i = 0; i < (KC * DIM / 4) / BLK; ++i)   // 16 iters
            s4[tid + i * BLK] = g4[tid + i * BLK];
        if (tid < KC) esql[tid] = esq_g[tid];
    }

    // Two rows, PACKED: xp[j] = (xr0[j], xr1[j]) — 128 VGPRs.
    float2 xp[DIM];
    {
        const float4* xv0 = reinterpret_cast<const float4*>(x + (size_t)row0 * DIM);
        const float4* xv1 = reinterpret_cast<const float4*>(x + (size_t)row1 * DIM);
#pragma unroll
        for (int j = 0; j < DIM / 4; ++j) {
            float4 v0 = xv0[j], v1 = xv1[j];
            xp[4 * j + 0] = make_float2(v0.x, v1.x);
            xp[4 * j + 1] = make_float2(v0.y, v1.y);
            xp[4 * j + 2] = make_float2(v0.z, v1.z);
            xp[4 * j + 3] = make_float2(v0.w, v1.w);
        }
    }

    // numpy-exact ||x||^2, both rows at once in float2 (element-independent:
    // each half is its own IEEE op => per-row results identical to scalar).
    float xsq0, xsq1;
    {
#pragma clang fp contract(off)
        float2 r[8];
#pragma unroll
        for (int j = 0; j < 8; ++j) {
            r[j].x = xp[j].x * xp[j].x;
            r[j].y = xp[j].y * xp[j].y;
        }
#pragma unroll
        for (int i = 8; i < 64; i += 8)
#pragma unroll
            for (int j = 0; j < 8; ++j) {
                r[j].x = r[j].x + xp[i + j].x * xp[i + j].x;
                r[j].y = r[j].y + xp[i + j].y * xp[i + j].y;
            }
        const float2 t0 = make_float2(r[0].x + r[1].x, r[0].y + r[1].y);
        const float2 t1 = make_float2(r[2].x + r[3].x, r[2].y + r[3].y);
        const float2 t2 = make_float2(r[4].x + r[5].x, r[4].y + r[5].y);
        const float2 t3 = make_float2(r[6].x + r[7].x, r[6].y + r[7].y);
        xsq0 = (t0.x + t1.x) + (t2.x + t3.x);
        xsq1 = (t0.y + t1.y) + (t2.y + t3.y);
    }

    __syncthreads();   // staging complete

    // 2 codes x 2 rows per iter; rows packed => 2 pk-FMA chains (a,b codes),
    // dep distance 2 instr x 2 cyc = 4 cyc = FMA latency. Each 16B LDS
    // broadcast read feeds 8 FMAs (4 pk instrs).
    float best0 = 3.4e38f, best1 = 3.4e38f;
    int bidx0 = 0, bidx1 = 0;
#pragma unroll 1
    for (int k = 0; k < KC; k += 2) {
        const float4* ea = reinterpret_cast<const float4*>(cbs + k * DIM);
        const float4* eb = ea + DIM / 4;
        float2 acca = make_float2(0.f, 0.f);   // (dot[row0][k], dot[row1][k])
        float2 accb = make_float2(0.f, 0.f);   // (dot[row0][k+1], dot[row1][k+1])
#pragma unroll
        for (int c = 0; c < DIM / 4; ++c) {
            const float4 a = ea[c];
            const float4 b = eb[c];
            float2 alo = make_float2(a.x, a.y), ahi = make_float2(a.z, a.w);
            float2 blo = make_float2(b.x, b.y), bhi = make_float2(b.z, b.w);
            // ascending j = 4c, 4c+1, 4c+2, 4c+3 for BOTH chains:
            PK_FMA_ELO(acca, xp[4 * c + 0], alo);   // e[4c]
            PK_FMA_ELO(accb, xp[4 * c + 0], blo);
            PK_FMA_EHI(acca, xp[4 * c + 1], alo);   // e[4c+1]
            PK_FMA_EHI(accb, xp[4 * c + 1], blo);
            PK_FMA_ELO(acca, xp[4 * c + 2], ahi);   // e[4c+2]
            PK_FMA_ELO(accb, xp[4 * c + 2], bhi);
            PK_FMA_EHI(acca, xp[4 * c + 3], ahi);   // e[4c+3]
            PK_FMA_EHI(accb, xp[4 * c + 3], bhi);
        }
        const float dot00 = acca.x, dot10 = acca.y;   // rows 0,1 vs code k
        const float dot01 = accb.x, dot11 = accb.y;   // rows 0,1 vs code k+1
        float d00, d01, d10, d11;
        {
#pragma clang fp contract(off)
            const float e0 = esql[k + 0], e1 = esql[k + 1];
            d00 = (xsq0 + e0) - 2.0f * dot00;  // 2*dot exact; each op rounds
            d01 = (xsq0 + e1) - 2.0f * dot01;
            d10 = (xsq1 + e0) - 2.0f * dot10;
            d11 = (xsq1 + e1) - 2.0f * dot11;
        }
        // strict <, ascending k: first-min-wins preserved (per row).
        if (d00 < best0) { best0 = d00; bidx0 = k + 0; }
        if (d01 < best0) { best0 = d01; bidx0 = k + 1; }
        if (d10 < best1) { best1 = d10; bidx1 = k + 0; }
        if (d11 < best1) { best1 = d11; bidx1 = k + 1; }
    }

    // ---- wave-cooperative coalesced epilogue (R3-proven), once per row-set ----
    // LDS gather: lane l reads cbs[idx*64 + l] -> 2-way bank aliasing = free.
    const size_t wave_row0 = (size_t)row0 - lane;
#pragma unroll 4
    for (int l = 0; l < 64; ++l) {
        const int idx = __shfl(bidx0, l, 64);
        out[1 + (wave_row0 + l) * DIM + lane] = cbs[idx * DIM + lane];
    }
    const size_t wave_row1 = (size_t)row1 - lane;
#pragma unroll 4
    for (int l = 0; l < 64; ++l) {
        const int idx = __shfl(bidx1, l, 64);
        out[1 + (wave_row1 + l) * DIM + lane] = cbs[idx * DIM + lane];
    }

    out[1 + (size_t)N_ROWS * DIM + row0] = (float)bidx0;  // coalesced
    out[1 + (size_t)N_ROWS * DIM + row1] = (float)bidx1;

    // loss contribution: sum of both rows' ||x - e||^2 (noise ~1e-5, thr ~2%)
    float lrow = best0 + best1;
#pragma unroll
    for (int off = 32; off > 0; off >>= 1) lrow += __shfl_down(lrow, off, 64);
    if (lane == 0) atomicAdd(loss_acc, lrow);
}

// ---- kernel 3: finalize loss ----
__global__ void fin_kernel(const float* __restrict__ loss_acc,
                           float* __restrict__ out) {
    if (threadIdx.x == 0) {
        float mean_sq = (*loss_acc) / (float)((size_t)N_ROWS * DIM);
        out[0] = 1.25f * mean_sq;  // q_loss + COMMITMENT_COST * e_loss
    }
}

extern "C" void kernel_launch(void* const* d_in, const int* in_sizes, int n_in,
                              void* d_out, int out_size, void* d_ws, size_t ws_size,
                              hipStream_t stream) {
    const float* x  = (const float*)d_in[0];
    const float* cb = (const float*)d_in[1];
    float* out = (float*)d_out;

    float* loss_acc = (float*)d_ws;                 // 4 B accumulator
    float* esq      = (float*)((char*)d_ws + 256);  // 512 floats

    hipMemsetAsync(d_ws, 0, 4, stream);             // zero loss accumulator
    esq_kernel<<<2, 256, 0, stream>>>(cb, esq);
    vq_kernel<<<N_ROWS / (BLK * RPT), BLK, LDS_FLOATS * sizeof(float), stream>>>(
        x, cb, esq, out, loss_acc);
    fin_kernel<<<1, 64, 0, stream>>>(loss_acc, out);
}

// Round 10
// 340.685 us; speedup vs baseline: 1.1387x; 1.1387x over previous
//
#include <hip/hip_runtime.h>
#include <hip/hip_bf16.h>

// Problem constants (fixed by reference): N=262144 rows, D=64, K=512 codes.
#define N_ROWS 262144
#define DIM 64
#define KC 512
#define BLK 512                        // threads/block; 8 waves = 2/SIMD, 1 block/CU
#define RPT 2                          // rows per thread
#define LDS_FLOATS (KC * DIM + KC)     // codebook + esq = 33280 floats = 133120 B

// d_out layout — FLOAT32 (verified passing):
//   out[0]                      = loss
//   out[1 .. 1+N*D)             = quantized [N,64] row-major
//   out[1+N*D .. 1+N*D+N)       = float(encoding_indices)
//
// Numerics replicated exactly (indices must match np.argmin of f32 dists):
//   x_sq, e_sq : numpy pairwise sum, n=64 => 8-accumulator striped scheme
//   dot        : sequential fused-FMA chain, ascending j (OpenBLAS kernel)
//   d          : fl( fl(x_sq + e_sq_k) - 2*dot_k ), contraction off
//   argmin     : strict <, first-min-wins (k ascending)
//
// R9 post-mortem: v_pk_fma_f32 is NOT double-rate on gfx950 (157 TF fp32
// peak IS the scalar v_fmac rate); per-instr asm also wrecked ds_read
// scheduling: 276->342us. REVERTED to R8's scalar chains.
// R8 residual: VALU busy 177us, LDS ~109us, wall 276 => ~100us both-waves
// lgkm stall: compiler issues 2 ds_read_b128 + 16 dependent FMAs per
// c-step (32-cyc window < 64+cyc LDS latency) and unroll-1 blocks load
// motion across the k backedge.
// R10: source-level software pipeline, depth 4 chunks. Ring sa[4]/sb[4]
// (c-loop fully unrolled => compile-time indices => registers). Consume
// chunk c (loaded 4 steps = ~144 issue-cyc earlier), prefetch chunk c+4,
// crossing into the next code-pair at c>=12. Tail prefetch (k=510) lands
// in the esql LDS region - in-bounds, never consumed. FMA chains and all
// numerics BIT-IDENTICAL to R8; only load scheduling changes.

// numpy pairwise sum of squares for n=64 (scalar path, PW_BLOCKSIZE=128).
__device__ __forceinline__ float np_sumsq64(const float* a) {
#pragma clang fp contract(off)
    float r[8];
#pragma unroll
    for (int j = 0; j < 8; ++j) r[j] = a[j] * a[j];
#pragma unroll
    for (int i = 8; i < 64; i += 8)
#pragma unroll
        for (int j = 0; j < 8; ++j) r[j] = r[j] + a[i + j] * a[i + j];
    return ((r[0] + r[1]) + (r[2] + r[3])) + ((r[4] + r[5]) + (r[6] + r[7]));
}

// ---- kernel 1: e_sq_k with numpy bit-exact summation ----
__global__ void esq_kernel(const float* __restrict__ cb, float* __restrict__ esq) {
    int k = blockIdx.x * blockDim.x + threadIdx.x;
    if (k < KC) esq[k] = np_sumsq64(cb + k * DIM);
}

// ---- kernel 2: main VQ — TWO rows per thread, codebook in LDS, dbuf loads ----
__global__ __launch_bounds__(BLK)
__attribute__((amdgpu_waves_per_eu(2, 2)))   // grid-exact occupancy; 256-VGPR budget
void vq_kernel(
    const float* __restrict__ x, const float* __restrict__ cb,
    const float* __restrict__ esq_g, float* __restrict__ out,
    float* __restrict__ loss_acc)
{
    extern __shared__ float smem[];
    float* cbs  = smem;             // [512*64] codebook, k-major (global layout)
    float* esql = smem + KC * DIM;  // [512]

    const int tid  = threadIdx.x;
    const int lane = tid & 63;
    const int row0 = blockIdx.x * (BLK * RPT) + tid;   // rows row0 and row0+BLK
    const int row1 = row0 + BLK;

    // ---- cooperative stage: 128KB codebook + 2KB esq, fully coalesced ----
    {
        const float4* g4 = reinterpret_cast<const float4*>(cb);
        float4*       s4 = reinterpret_cast<float4*>(cbs);
#pragma unroll
        for (int i = 0; i < (KC * DIM / 4) / BLK; ++i)   // 16 iters
            s4[tid + i * BLK] = g4[tid + i * BLK];
        if (tid < KC) esql[tid] = esq_g[tid];
    }

    // Two rows into 128 VGPRs — overlaps staging latency.
    float xr0[DIM], xr1[DIM];
    {
        const float4* xv0 = reinterpret_cast<const float4*>(x + (size_t)row0 * DIM);
        const float4* xv1 = reinterpret_cast<const float4*>(x + (size_t)row1 * DIM);
#pragma unroll
        for (int j = 0; j < DIM / 4; ++j) {
            float4 v0 = xv0[j], v1 = xv1[j];
            xr0[4 * j + 0] = v0.x; xr0[4 * j + 1] = v0.y;
            xr0[4 * j + 2] = v0.z; xr0[4 * j + 3] = v0.w;
            xr1[4 * j + 0] = v1.x; xr1[4 * j + 1] = v1.y;
            xr1[4 * j + 2] = v1.z; xr1[4 * j + 3] = v1.w;
        }
    }

    // numpy-exact ||x||^2 per row.
    const float xsq0 = np_sumsq64(xr0);
    const float xsq1 = np_sumsq64(xr1);

    __syncthreads();   // staging complete

    // Chunked view: code k = float4s cb4[k*16 .. k*16+15].
    const float4* cb4 = reinterpret_cast<const float4*>(cbs);

    // Prologue: chunks 0..3 of pair (codes 0, 1) into the ring.
    float4 sa[4], sb[4];
#pragma unroll
    for (int i = 0; i < 4; ++i) { sa[i] = cb4[i]; sb[i] = cb4[16 + i]; }

    // 2 codes x 2 rows per iter = 4 independent sequential fused-FMA chains.
    // Ring-buffered loads run 4 chunks (~144 issue-cyc) ahead of their use.
    float best0 = 3.4e38f, best1 = 3.4e38f;
    int bidx0 = 0, bidx1 = 0;
#pragma unroll 1
    for (int k = 0; k < KC; k += 2) {
        const float4* base = cb4 + (size_t)k * 16;   // [0..15]=code k, [16..31]=code k+1
        float dot00 = 0.f, dot01 = 0.f, dot10 = 0.f, dot11 = 0.f;
#pragma unroll
        for (int c = 0; c < 16; ++c) {               // fully unrolled: c compile-time
            const float4 a = sa[c & 3];
            const float4 b = sb[c & 3];
            // Prefetch chunk c+4 of this pair, or chunk c-12 of the NEXT pair.
            if (c < 12) {
                sa[c & 3] = base[c + 4];
                sb[c & 3] = base[16 + c + 4];
            } else {
                sa[c & 3] = base[32 + (c - 12)];     // next pair code k+2
                sb[c & 3] = base[48 + (c - 12)];     // next pair code k+3
            }
            // ascending j = 4c..4c+3 within each chain (bit-exact R8 order)
            dot00 = fmaf(xr0[4 * c + 0], a.x, dot00);
            dot01 = fmaf(xr0[4 * c + 0], b.x, dot01);
            dot10 = fmaf(xr1[4 * c + 0], a.x, dot10);
            dot11 = fmaf(xr1[4 * c + 0], b.x, dot11);
            dot00 = fmaf(xr0[4 * c + 1], a.y, dot00);
            dot01 = fmaf(xr0[4 * c + 1], b.y, dot01);
            dot10 = fmaf(xr1[4 * c + 1], a.y, dot10);
            dot11 = fmaf(xr1[4 * c + 1], b.y, dot11);
            dot00 = fmaf(xr0[4 * c + 2], a.z, dot00);
            dot01 = fmaf(xr0[4 * c + 2], b.z, dot01);
            dot10 = fmaf(xr1[4 * c + 2], a.z, dot10);
            dot11 = fmaf(xr1[4 * c + 2], b.z, dot11);
            dot00 = fmaf(xr0[4 * c + 3], a.w, dot00);
            dot01 = fmaf(xr0[4 * c + 3], b.w, dot01);
            dot10 = fmaf(xr1[4 * c + 3], a.w, dot10);
            dot11 = fmaf(xr1[4 * c + 3], b.w, dot11);
        }
        float d00, d01, d10, d11;
        {
#pragma clang fp contract(off)
            const float e0 = esql[k + 0], e1 = esql[k + 1];
            d00 = (xsq0 + e0) - 2.0f * dot00;  // 2*dot exact; each op rounds
            d01 = (xsq0 + e1) - 2.0f * dot01;
            d10 = (xsq1 + e0) - 2.0f * dot10;
            d11 = (xsq1 + e1) - 2.0f * dot11;
        }
        // strict <, ascending k: first-min-wins preserved (per row).
        if (d00 < best0) { best0 = d00; bidx0 = k + 0; }
        if (d01 < best0) { best0 = d01; bidx0 = k + 1; }
        if (d10 < best1) { best1 = d10; bidx1 = k + 0; }
        if (d11 < best1) { best1 = d11; bidx1 = k + 1; }
    }

    // ---- wave-cooperative coalesced epilogue (R3-proven), once per row-set ----
    // LDS gather: lane l reads cbs[idx*64 + l] -> 2-way bank aliasing = free.
    const size_t wave_row0 = (size_t)row0 - lane;
#pragma unroll 4
    for (int l = 0; l < 64; ++l) {
        const int idx = __shfl(bidx0, l, 64);
        out[1 + (wave_row0 + l) * DIM + lane] = cbs[idx * DIM + lane];
    }
    const size_t wave_row1 = (size_t)row1 - lane;
#pragma unroll 4
    for (int l = 0; l < 64; ++l) {
        const int idx = __shfl(bidx1, l, 64);
        out[1 + (wave_row1 + l) * DIM + lane] = cbs[idx * DIM + lane];
    }

    out[1 + (size_t)N_ROWS * DIM + row0] = (float)bidx0;  // coalesced
    out[1 + (size_t)N_ROWS * DIM + row1] = (float)bidx1;

    // loss contribution: sum of both rows' ||x - e||^2 (noise ~1e-5, thr ~2%)
    float lrow = best0 + best1;
#pragma unroll
    for (int off = 32; off > 0; off >>= 1) lrow += __shfl_down(lrow, off, 64);
    if (lane == 0) atomicAdd(loss_acc, lrow);
}

// ---- kernel 3: finalize loss ----
__global__ void fin_kernel(const float* __restrict__ loss_acc,
                           float* __restrict__ out) {
    if (threadIdx.x == 0) {
        float mean_sq = (*loss_acc) / (float)((size_t)N_ROWS * DIM);
        out[0] = 1.25f * mean_sq;  // q_loss + COMMITMENT_COST * e_loss
    }
}

extern "C" void kernel_launch(void* const* d_in, const int* in_sizes, int n_in,
                              void* d_out, int out_size, void* d_ws, size_t ws_size,
                              hipStream_t stream) {
    const float* x  = (const float*)d_in[0];
    const float* cb = (const float*)d_in[1];
    float* out = (float*)d_out;

    float* loss_acc = (float*)d_ws;                 // 4 B accumulator
    float* esq      = (float*)((char*)d_ws + 256);  // 512 floats

    hipMemsetAsync(d_ws, 0, 4, stream);             // zero loss accumulator
    esq_kernel<<<2, 256, 0, stream>>>(cb, esq);
    vq_kernel<<<N_ROWS / (BLK * RPT), BLK, LDS_FLOATS * sizeof(float), stream>>>(
        x, cb, esq, out, loss_acc);
    fin_kernel<<<1, 64, 0, stream>>>(loss_acc, out);
}